// Round 9
// baseline (382.301 us; speedup 1.0000x reference)
//
#include <hip/hip_runtime.h>

#define T_SEQ 2048
#define DM    2048
#define NH    16
#define HD    128
#define NROW  4096   // B*T

typedef __attribute__((ext_vector_type(8))) short short8;
typedef __attribute__((ext_vector_type(4))) float f32x4;
typedef __attribute__((ext_vector_type(16))) float f32x16;

static __device__ __forceinline__ float bf2f(unsigned short h) {
    unsigned int u = ((unsigned int)h) << 16;
    return __builtin_bit_cast(float, u);
}
static __device__ __forceinline__ unsigned short f2bf(float f) {
    unsigned int u = __builtin_bit_cast(unsigned int, f);
    u += 0x7FFFu + ((u >> 16) & 1u);
    return (unsigned short)(u >> 16);
}
// cheap round-half-up bf16 (2 VALU ops) for P/O inner-loop conversions
static __device__ __forceinline__ unsigned short bf_fast(float f) {
    return (unsigned short)((__builtin_bit_cast(unsigned int, f) + 0x8000u) >> 16);
}

typedef __attribute__((address_space(1))) const unsigned int gas_uint;
typedef __attribute__((address_space(3))) unsigned int las_uint;

static __device__ __forceinline__ void load_lds16(const void* g, void* l) {
    __builtin_amdgcn_global_load_lds((gas_uint*)g, (las_uint*)l, 16, 0, 0);
}

static __device__ __forceinline__ f32x4 mfma_bf16(short8 a, short8 b, f32x4 c) {
    return __builtin_amdgcn_mfma_f32_16x16x32_bf16(a, b, c, 0, 0, 0);
}
static __device__ __forceinline__ f32x16 mfma32_bf16(short8 a, short8 b, f32x16 c) {
    return __builtin_amdgcn_mfma_f32_32x32x16_bf16(a, b, c, 0, 0, 0);
}

// ---------------- prep: z<4 -> transpose+cast W[k][n] f32 -> Wt[n][k] bf16 (64x64 tiles,
// float4 loads, bf16 LDS tile); z==4 -> cast x f32 -> bf16 (8 x float4 per thread) ------
__global__ __launch_bounds__(256) void k_prep(const float* __restrict__ x,
                                              unsigned short* __restrict__ xb,
                                              const float* __restrict__ w0, const float* __restrict__ w1,
                                              const float* __restrict__ w2, const float* __restrict__ w3,
                                              unsigned short* __restrict__ t0, unsigned short* __restrict__ t1,
                                              unsigned short* __restrict__ t2, unsigned short* __restrict__ t3) {
    const int tid = threadIdx.x;
    const int z = blockIdx.z;
    if (z == 4) {
        // cast: 1024 blocks cover NROW*DM = 8M elems; 8 x float4 per thread
        const int iblock = blockIdx.y * 32 + blockIdx.x;
#pragma unroll
        for (int i = 0; i < 8; ++i) {
            int idx = (iblock * 2048 + i * 256 + tid) * 4;
            float4 v = *(const float4*)(x + idx);
            ushort4 o;
            o.x = f2bf(v.x); o.y = f2bf(v.y); o.z = f2bf(v.z); o.w = f2bf(v.w);
            *(ushort4*)(xb + idx) = o;
        }
        return;
    }
    __shared__ unsigned short tile[64][68];   // tile[k][n], bf16
    const float* W = (z == 0) ? w0 : (z == 1) ? w1 : (z == 2) ? w2 : w3;
    unsigned short* Wt = (z == 0) ? t0 : (z == 1) ? t1 : (z == 2) ? t2 : t3;
    const int bx = blockIdx.x * 64;  // n base
    const int by = blockIdx.y * 64;  // k base
    const int rr = tid >> 4, cc = (tid & 15) * 4;
#pragma unroll
    for (int it = 0; it < 4; ++it) {
        int row = it * 16 + rr;      // k offset
        float4 v = *(const float4*)(W + (size_t)(by + row) * DM + bx + cc);
        ushort4 o;
        o.x = f2bf(v.x); o.y = f2bf(v.y); o.z = f2bf(v.z); o.w = f2bf(v.w);
        *(ushort4*)&tile[row][cc] = o;
    }
    __syncthreads();
#pragma unroll
    for (int it = 0; it < 4; ++it) {
        int ln = it * 16 + rr;       // n offset
        ushort4 v;
#pragma unroll
        for (int j = 0; j < 4; ++j) v = (j == 0) ? (ushort4){tile[cc][ln], 0, 0, 0} : v, ((unsigned short*)&v)[j] = tile[cc + j][ln];
        *(ushort4*)(Wt + (size_t)(bx + ln) * DM + by + cc) = v;
    }
}

// ---------------- 128x128 GEMM, A[M][K] bf16 @ Bt[N][K] bf16 ----------------
// K-loop FROZEN (107 us qkv, 43% MfmaUtil, 0 bank conflicts) — two pipelined
// rewrites (r1, r3) both regressed to ~30% MfmaUtil. Epilogue modes:
//   MODE 0: bf16 C (Q)          MODE 1: f32 C (attn-out)
//   MODE 2: bf16 C -> LDS transpose tile -> COALESCED Vt[(b*16+h)*128+d][t] rows
//           (r7 wrote direct at 4KB stride: 16x8B scatter/instr -> +10us, +8MB FETCH;
//            r8 bug: read-out loop covered only rows 0..63 -> r9 fix: 16 iterations)
//   MODE 3: bf16 C + RoPE via LDS tile (pairs d, d+64)         (kills k_rope_k)
// smem: caller-provided (>= 16896 ushorts; As=smem, Bs=smem+8192).
template <int MODE>
static __device__ __forceinline__ void gemm_body(unsigned short* smem,
                                                 const unsigned short* __restrict__ A,
                                                 const unsigned short* __restrict__ Bt,
                                                 unsigned short* __restrict__ Cb,
                                                 float* __restrict__ Cf,
                                                 const float* __restrict__ cosp,
                                                 const float* __restrict__ sinp) {
    unsigned short* As = smem;
    unsigned short* Bs = smem + 8192;
    const int tid = threadIdx.x;
    const int w = tid >> 6, lane = tid & 63;
    const int col = lane & 15, quad = lane >> 4;
    const int wm = w >> 1, wn = w & 1;
    const size_t m0 = (size_t)blockIdx.y * 128;
    const size_t n0 = (size_t)blockIdx.x * 128;

    f32x4 acc[4][4];
#pragma unroll
    for (int i = 0; i < 4; ++i)
#pragma unroll
        for (int j = 0; j < 4; ++j)
            acc[i][j] = (f32x4){0.f, 0.f, 0.f, 0.f};

    const int lrow = lane >> 3;                 // 0..7 row within 8-row chunk
    const int gcol = ((lane & 7) ^ lrow) * 8;   // XOR-swizzled logical col (elems)

    for (int k0 = 0; k0 < DM; k0 += 64) {
#pragma unroll
        for (int c = w; c < 16; c += 4) {
            load_lds16(A + (m0 + c * 8 + lrow) * DM + k0 + gcol, &As[c * 512]);
            load_lds16(Bt + (n0 + c * 8 + lrow) * DM + k0 + gcol, &Bs[c * 512]);
        }
        __syncthreads();
#pragma unroll
        for (int ks = 0; ks < 2; ++ks) {
            short8 af[4], bf[4];
            int g = ks * 4 + quad;
#pragma unroll
            for (int mt = 0; mt < 4; ++mt) {
                int r = wm * 64 + mt * 16 + col;
                af[mt] = *(const short8*)&As[r * 64 + ((g ^ (r & 7)) * 8)];
            }
#pragma unroll
            for (int nt = 0; nt < 4; ++nt) {
                int r = wn * 64 + nt * 16 + col;
                bf[nt] = *(const short8*)&Bs[r * 64 + ((g ^ (r & 7)) * 8)];
            }
#pragma unroll
            for (int mt = 0; mt < 4; ++mt)
#pragma unroll
                for (int nt = 0; nt < 4; ++nt)
                    acc[mt][nt] = mfma_bf16(af[mt], bf[nt], acc[mt][nt]);
        }
        __syncthreads();
    }

    if (MODE == 0 || MODE == 1) {
#pragma unroll
        for (int mt = 0; mt < 4; ++mt)
#pragma unroll
            for (int nt = 0; nt < 4; ++nt)
#pragma unroll
                for (int reg = 0; reg < 4; ++reg) {
                    size_t r = m0 + wm * 64 + mt * 16 + quad * 4 + reg;
                    size_t c = n0 + wn * 64 + nt * 16 + col;
                    if (MODE == 1) Cf[r * DM + c] = acc[mt][nt][reg];
                    else           Cb[r * DM + c] = f2bf(acc[mt][nt][reg]);
                }
    } else if (MODE == 2) {
        // V: transpose via LDS tile [c_local][t_local], stride 132 (264 B == 0 mod 8:
        // all ushort4 accesses 8B-aligned; conflict-free), then coalesced row writes.
        unsigned short* tile = smem;   // 128*132 = 16896 ushorts
        const int tbl = wm * 64 + quad * 4;   // t_local base
#pragma unroll
        for (int mt = 0; mt < 4; ++mt)
#pragma unroll
            for (int nt = 0; nt < 4; ++nt) {
                const int cl = wn * 64 + nt * 16 + col;   // c local
                ushort4 v;
#pragma unroll
                for (int reg = 0; reg < 4; ++reg)
                    ((unsigned short*)&v)[reg] = f2bf(acc[mt][nt][reg]);
                *(ushort4*)&tile[cl * 132 + tbl + mt * 16] = v;
            }
        __syncthreads();
        const int bb = (int)(m0 >> 11);          // batch
        const int tg = (int)m0 & 2047;           // t base of this tile
        // 16 iters x 256 thr x 4 elems = 16384 = full 128x128 tile (r8 had 8 -> half)
#pragma unroll
        for (int i = 0; i < 16; ++i) {
            const int task = i * 256 + tid;      // 0..4095
            const int cl = task >> 5;            // 0..127 (row of Vt)
            const int tp = (task & 31) * 4;      // 0..124 (t offset, ushort4)
            ushort4 v = *(const ushort4*)&tile[cl * 132 + tp];
            *(ushort4*)(Cb + (size_t)(bb * 2048 + (int)n0 + cl) * T_SEQ + tg + tp) = v;
        }
    } else {
        // K: bf16 -> LDS tile [128][132] (128 cols + 4 pad), then RoPE pairs (d, d+64).
        // Bit-identical to old gemm->f2bf->k_rope_k path (bf16 intermediate kept).
        unsigned short* tile = smem;   // 128*132 = 16896 ushorts
#pragma unroll
        for (int mt = 0; mt < 4; ++mt)
#pragma unroll
            for (int nt = 0; nt < 4; ++nt)
#pragma unroll
                for (int reg = 0; reg < 4; ++reg) {
                    const int rl = wm * 64 + mt * 16 + quad * 4 + reg;
                    const int cl = wn * 64 + nt * 16 + col;
                    tile[rl * 132 + cl] = f2bf(acc[mt][nt][reg]);
                }
        __syncthreads();
#pragma unroll
        for (int i = 0; i < 8; ++i) {
            const int task = i * 256 + tid;
            const int rl = task >> 4;            // 0..127
            const int d4 = (task & 15) * 4;      // 0..60
            const int r = (int)m0 + rl;
            const int t = r & (T_SEQ - 1);
            ushort4 x1 = *(const ushort4*)&tile[rl * 132 + d4];
            ushort4 x2 = *(const ushort4*)&tile[rl * 132 + d4 + 64];
            float4 c = *(const float4*)(cosp + t * 64 + d4);
            float4 s = *(const float4*)(sinp + t * 64 + d4);
            ushort4 o1, o2;
#pragma unroll
            for (int q = 0; q < 4; ++q) {
                float a1 = bf2f(((const unsigned short*)&x1)[q]);
                float a2 = bf2f(((const unsigned short*)&x2)[q]);
                float cc = ((const float*)&c)[q], ss = ((const float*)&s)[q];
                ((unsigned short*)&o1)[q] = f2bf(a1 * cc - a2 * ss);
                ((unsigned short*)&o2)[q] = f2bf(a1 * ss + a2 * cc);
            }
            *(ushort4*)(Cb + (size_t)r * DM + n0 + d4)      = o1;
            *(ushort4*)(Cb + (size_t)r * DM + n0 + d4 + 64) = o2;
        }
    }
}

__global__ __launch_bounds__(256) void k_gemm_qkv(const unsigned short* __restrict__ xb,
                                                  const unsigned short* __restrict__ wtq,
                                                  const unsigned short* __restrict__ wtk,
                                                  const unsigned short* __restrict__ wtv,
                                                  unsigned short* __restrict__ qb,
                                                  unsigned short* __restrict__ kb,
                                                  unsigned short* __restrict__ vt,
                                                  const float* __restrict__ cosp,
                                                  const float* __restrict__ sinp) {
    __shared__ unsigned short smem[16896];   // 33 KiB: As/Bs (16K) or epilogue tile (16.9K)
    const int z = blockIdx.z;
    if (z == 0)      gemm_body<0>(smem, xb, wtq, qb, nullptr, nullptr, nullptr);
    else if (z == 1) gemm_body<3>(smem, xb, wtk, kb, nullptr, cosp, sinp);
    else             gemm_body<2>(smem, xb, wtv, vt, nullptr, nullptr, nullptr);
}

__global__ __launch_bounds__(256) void k_gemm_out(const unsigned short* __restrict__ ob,
                                                  const unsigned short* __restrict__ wto,
                                                  float* __restrict__ out) {
    __shared__ unsigned short smem[16384];
    gemm_body<1>(smem, ob, wto, nullptr, out, nullptr, nullptr);
}

// ---------------- causal flash attention, 32x32x16 MFMA, S^T formulation ----------------
// grid flat 512 blocks; LPT remap: j = 15 - (flat>>5) so longest blocks dispatch first.
// Block = 128 queries (4 waves x 32). Wave: S^T = K·Q^T (A=K-frag, B=Q-frag);
// per-lane softmax (col=query, 32 in-lane keys + shfl_xor(32));
// P^T -> per-wave LDS -> B-operand; O^T = V^T·P^T.
// r8: setprio REMOVED (r2->r5 A/B: setprio+defermax was net +8.8us; m190 says setprio
// hurts in barrier-lockstep multi-wave blocks). defer-max KEPT (VALU-saving, sound).
#define PST 72
__global__ __launch_bounds__(256) void k_flash(const unsigned short* __restrict__ Q,
                                               const unsigned short* __restrict__ K,
                                               const unsigned short* __restrict__ Vt,
                                               unsigned short* __restrict__ O,
                                               const float* __restrict__ cosp,
                                               const float* __restrict__ sinp) {
    __shared__ unsigned short Ks[64 * 128];
    __shared__ unsigned short Vs[128 * 64];
    __shared__ unsigned short Ps[4][32 * PST];
    const int tid = threadIdx.x;
    const int w = tid >> 6, lane = tid & 63;
    const int col = lane & 31, l5 = lane >> 5;
    const int flat = blockIdx.x | (blockIdx.y << 4) | (blockIdx.z << 8);
    const int j = 15 - (flat >> 5);
    const int hb = flat & 31;
    const int h = hb & 15, b = hb >> 4;
    const int q0 = j * 128;
    const size_t rowbase = ((size_t)b * T_SEQ) * DM + (size_t)h * HD;
    const size_t hbase = ((size_t)b * NH + h) * HD;
    const float SCL = 0.088388347648318447f * 1.4426950408889634f;  // 1/sqrt(D) * log2(e)
    unsigned short* Pw = &Ps[w][0];

    const int t = q0 + w * 32 + col;     // this lane's query
    // ---- load Q fragments (B-layout: q=col, k=l5*8+jj per 16-chunk) + in-reg RoPE ----
    short8 qf[8];
    {
        const unsigned short* qp = Q + rowbase + (size_t)t * DM + l5 * 8;
#pragma unroll
        for (int st = 0; st < 8; ++st)
            qf[st] = *(const short8*)(qp + st * 16);
        const float* cp = cosp + t * 64 + l5 * 8;
        const float* sp = sinp + t * 64 + l5 * 8;
#pragma unroll
        for (int st = 0; st < 4; ++st) {
            float4 c0 = *(const float4*)(cp + st * 16);
            float4 c1 = *(const float4*)(cp + st * 16 + 4);
            float4 s0v = *(const float4*)(sp + st * 16);
            float4 s1v = *(const float4*)(sp + st * 16 + 4);
#pragma unroll
            for (int jj = 0; jj < 8; ++jj) {
                float cv = ((jj < 4) ? ((const float*)&c0)[jj] : ((const float*)&c1)[jj - 4]) * SCL;
                float sv = ((jj < 4) ? ((const float*)&s0v)[jj] : ((const float*)&s1v)[jj - 4]) * SCL;
                float a1 = bf2f((unsigned short)qf[st][jj]);
                float a2 = bf2f((unsigned short)qf[st + 4][jj]);
                qf[st][jj]     = (short)f2bf(a1 * cv - a2 * sv);
                qf[st + 4][jj] = (short)f2bf(a1 * sv + a2 * cv);
            }
        }
    }

    f32x16 o[4];
#pragma unroll
    for (int i = 0; i < 4; ++i) o[i] = (f32x16)(0.f);
    float m_i = -1e30f, l_i = 0.f;

    const int kt_max = 2 * j + 1;
    const int kt_lim = (q0 + w * 32 + 31) >> 6;   // last k-tile this wave computes
    const int cswz = col & 7;

    for (int kt = 0; kt <= kt_max; ++kt) {
        const int k0 = kt * 64;
        __syncthreads();
        // stage K tile [64 keys][128 d] and V^T tile [128 d][64 keys], XOR-swizzled
#pragma unroll
        for (int c = 0; c < 4; ++c) {
            const int c4 = w * 4 + c;
            const int krow = c4 * 4 + (lane >> 4);
            const int kpos = lane & 15;
            load_lds16(K + rowbase + (size_t)(k0 + krow) * DM + ((kpos ^ (krow & 7)) * 8),
                       &Ks[c4 * 512]);
            const int vrow = c4 * 8 + (lane >> 3);
            const int vpos = lane & 7;
            load_lds16(Vt + (hbase + vrow) * (size_t)T_SEQ + k0 + ((vpos ^ (vrow & 7)) * 8),
                       &Vs[c4 * 512]);
        }
        __syncthreads();
        if (kt > kt_lim) continue;   // wave-uniform; barriers still hit each iter

        // S^T = K·Q^T : two 32-key M-subtiles, 8 k-steps over D=128
        f32x16 s0 = (f32x16)(0.f), s1 = (f32x16)(0.f);
#pragma unroll
        for (int st = 0; st < 8; ++st) {
            const int dg = (2 * st + l5) ^ cswz;
            short8 kf0 = *(const short8*)&Ks[col * 128 + dg * 8];
            short8 kf1 = *(const short8*)&Ks[col * 128 + 4096 + dg * 8];
            s0 = mfma32_bf16(kf0, qf[st], s0);
            s1 = mfma32_bf16(kf1, qf[st], s1);
        }

        // causal mask (diag tiles only)
        if (k0 + 63 > q0 + w * 32) {
            const int kb = k0 + 4 * l5;
#pragma unroll
            for (int r = 0; r < 16; ++r) {
                const int key = kb + (r & 3) + 8 * (r >> 2);
                if (key > t) s0[r] = -1e30f;
                if (key + 32 > t) s1[r] = -1e30f;
            }
        }

        // per-lane online softmax (query=col; 32 in-lane keys + l5 partner)
        // T13 defer-max: if this tile's max is within THR=8 (log2 domain) of the
        // running max for ALL lanes of the wave, keep m_i (P bounded by 2^8; f32
        // accumulators unaffected; epilogue's 1/l_i divides the scaling out).
        float mx = -1e30f;
#pragma unroll
        for (int r = 0; r < 16; ++r) mx = fmaxf(mx, fmaxf(s0[r], s1[r]));
        mx = fmaxf(mx, __shfl_xor(mx, 32));
        if (!__all(mx - m_i <= 8.0f)) {
            const float mnew = fmaxf(m_i, mx);
            const float alpha = __builtin_amdgcn_exp2f(m_i - mnew);
            m_i = mnew;
            l_i *= alpha;
#pragma unroll
            for (int i = 0; i < 4; ++i) o[i] *= alpha;
        }
        float sum = 0.f;
#pragma unroll
        for (int r = 0; r < 16; ++r) {
            float p0 = __builtin_amdgcn_exp2f(s0[r] - m_i);
            float p1 = __builtin_amdgcn_exp2f(s1[r] - m_i);
            s0[r] = p0; s1[r] = p1;
            sum += p0 + p1;
        }
        sum += __shfl_xor(sum, 32);
        l_i += sum;

        // P^T -> per-wave LDS (runs of 4 consecutive keys per C-reg group)
#pragma unroll
        for (int g = 0; g < 4; ++g) {
            ushort4 a4, b4;
#pragma unroll
            for (int i = 0; i < 4; ++i) {
                ((unsigned short*)&a4)[i] = bf_fast(s0[g * 4 + i]);
                ((unsigned short*)&b4)[i] = bf_fast(s1[g * 4 + i]);
            }
            *(ushort4*)(Pw + col * PST + g * 8 + 4 * l5)      = a4;
            *(ushort4*)(Pw + col * PST + 32 + g * 8 + 4 * l5) = b4;
        }
        // read back as B-frags: keys st*16 + l5*8 + {0..7} for query col
        short8 pb[4];
#pragma unroll
        for (int st = 0; st < 4; ++st)
            pb[st] = *(const short8*)(Pw + col * PST + st * 16 + l5 * 8);

        // O^T += V^T·P^T : A = V-frag (d rows), B = P-frag
#pragma unroll
        for (int ms = 0; ms < 4; ++ms) {
            const int drow = (ms * 32 + col) * 64;
#pragma unroll
            for (int st = 0; st < 4; ++st) {
                const int kg = (2 * st + l5) ^ cswz;
                short8 vf = *(const short8*)&Vs[drow + kg * 8];
                o[ms] = mfma32_bf16(vf, pb[st], o[ms]);
            }
        }
    }

    // epilogue: lane holds query=col, d = ms*32 + g*8 + 4*l5 + {0..3}
    const float inv = __builtin_amdgcn_rcpf(l_i);
    unsigned short* op = O + rowbase + (size_t)t * DM;
#pragma unroll
    for (int ms = 0; ms < 4; ++ms)
#pragma unroll
        for (int g = 0; g < 4; ++g) {
            ushort4 st4;
#pragma unroll
            for (int i = 0; i < 4; ++i)
                ((unsigned short*)&st4)[i] = bf_fast(o[ms][g * 4 + i] * inv);
            *(ushort4*)(op + ms * 32 + g * 8 + 4 * l5) = st4;
        }
}

extern "C" void kernel_launch(void* const* d_in, const int* in_sizes, int n_in,
                              void* d_out, int out_size, void* d_ws, size_t ws_size,
                              hipStream_t stream) {
    const float* x    = (const float*)d_in[0];
    // d_in[1] = mask (unused; causal structure is known)
    const float* cosp = (const float*)d_in[2];
    const float* sinp = (const float*)d_in[3];
    const float* Wq   = (const float*)d_in[4];
    const float* Wk   = (const float*)d_in[5];
    const float* Wv   = (const float*)d_in[6];
    const float* Wo   = (const float*)d_in[7];
    float* out = (float*)d_out;

    unsigned short* xb  = (unsigned short*)d_ws;             // 4096*2048
    unsigned short* wtq = xb  + (size_t)NROW * DM;           // 2048*2048 each
    unsigned short* wtk = wtq + (size_t)DM * DM;
    unsigned short* wtv = wtk + (size_t)DM * DM;
    unsigned short* wto = wtv + (size_t)DM * DM;
    unsigned short* qb  = wto + (size_t)DM * DM;             // 4096*2048 each
    unsigned short* kb  = qb  + (size_t)NROW * DM;
    unsigned short* vt  = kb  + (size_t)NROW * DM;           // V written TRANSPOSED here
    unsigned short* ob  = vt  + (size_t)NROW * DM;

    hipLaunchKernelGGL(k_prep, dim3(32, 32, 5), dim3(256), 0, stream,
                       x, xb, Wq, Wk, Wv, Wo, wtq, wtk, wtv, wto);
    hipLaunchKernelGGL(k_gemm_qkv, dim3(16, 32, 3), dim3(256), 0, stream,
                       xb, wtq, wtk, wtv, qb, kb, vt, cosp, sinp);
    hipLaunchKernelGGL(k_flash, dim3(16, 16, 2), dim3(256), 0, stream,
                       qb, kb, vt, ob, cosp, sinp);
    hipLaunchKernelGGL(k_gemm_out, dim3(16, 32, 1), dim3(256), 0, stream, ob, wto, out);
}

// Round 10
// 374.182 us; speedup vs baseline: 1.0217x; 1.0217x over previous
//
#include <hip/hip_runtime.h>

#define T_SEQ 2048
#define DM    2048
#define NH    16
#define HD    128
#define NROW  4096   // B*T

typedef __attribute__((ext_vector_type(8))) short short8;
typedef __attribute__((ext_vector_type(4))) float f32x4;
typedef __attribute__((ext_vector_type(16))) float f32x16;

static __device__ __forceinline__ float bf2f(unsigned short h) {
    unsigned int u = ((unsigned int)h) << 16;
    return __builtin_bit_cast(float, u);
}
static __device__ __forceinline__ unsigned short f2bf(float f) {
    unsigned int u = __builtin_bit_cast(unsigned int, f);
    u += 0x7FFFu + ((u >> 16) & 1u);
    return (unsigned short)(u >> 16);
}
// cheap round-half-up bf16 (2 VALU ops) for P/O inner-loop conversions
static __device__ __forceinline__ unsigned short bf_fast(float f) {
    return (unsigned short)((__builtin_bit_cast(unsigned int, f) + 0x8000u) >> 16);
}
// pack two floats to bf16x2 in a u32 (lo in low 16)
static __device__ __forceinline__ unsigned int pk2(float lo, float hi) {
    return (unsigned int)bf_fast(lo) | ((unsigned int)bf_fast(hi) << 16);
}

typedef __attribute__((address_space(1))) const unsigned int gas_uint;
typedef __attribute__((address_space(3))) unsigned int las_uint;

static __device__ __forceinline__ void load_lds16(const void* g, void* l) {
    __builtin_amdgcn_global_load_lds((gas_uint*)g, (las_uint*)l, 16, 0, 0);
}

static __device__ __forceinline__ f32x4 mfma_bf16(short8 a, short8 b, f32x4 c) {
    return __builtin_amdgcn_mfma_f32_16x16x32_bf16(a, b, c, 0, 0, 0);
}
static __device__ __forceinline__ f32x16 mfma32_bf16(short8 a, short8 b, f32x16 c) {
    return __builtin_amdgcn_mfma_f32_32x32x16_bf16(a, b, c, 0, 0, 0);
}

// ---------------- prep: z<4 -> transpose+cast W[k][n] f32 -> Wt[n][k] bf16 (64x64 tiles,
// float4 loads, bf16 LDS tile); z==4 -> cast x f32 -> bf16 (8 x float4 per thread) ------
__global__ __launch_bounds__(256) void k_prep(const float* __restrict__ x,
                                              unsigned short* __restrict__ xb,
                                              const float* __restrict__ w0, const float* __restrict__ w1,
                                              const float* __restrict__ w2, const float* __restrict__ w3,
                                              unsigned short* __restrict__ t0, unsigned short* __restrict__ t1,
                                              unsigned short* __restrict__ t2, unsigned short* __restrict__ t3) {
    const int tid = threadIdx.x;
    const int z = blockIdx.z;
    if (z == 4) {
        // cast: 1024 blocks cover NROW*DM = 8M elems; 8 x float4 per thread
        const int iblock = blockIdx.y * 32 + blockIdx.x;
#pragma unroll
        for (int i = 0; i < 8; ++i) {
            int idx = (iblock * 2048 + i * 256 + tid) * 4;
            float4 v = *(const float4*)(x + idx);
            ushort4 o;
            o.x = f2bf(v.x); o.y = f2bf(v.y); o.z = f2bf(v.z); o.w = f2bf(v.w);
            *(ushort4*)(xb + idx) = o;
        }
        return;
    }
    __shared__ unsigned short tile[64][68];   // tile[k][n], bf16
    const float* W = (z == 0) ? w0 : (z == 1) ? w1 : (z == 2) ? w2 : w3;
    unsigned short* Wt = (z == 0) ? t0 : (z == 1) ? t1 : (z == 2) ? t2 : t3;
    const int bx = blockIdx.x * 64;  // n base
    const int by = blockIdx.y * 64;  // k base
    const int rr = tid >> 4, cc = (tid & 15) * 4;
#pragma unroll
    for (int it = 0; it < 4; ++it) {
        int row = it * 16 + rr;      // k offset
        float4 v = *(const float4*)(W + (size_t)(by + row) * DM + bx + cc);
        ushort4 o;
        o.x = f2bf(v.x); o.y = f2bf(v.y); o.z = f2bf(v.z); o.w = f2bf(v.w);
        *(ushort4*)&tile[row][cc] = o;
    }
    __syncthreads();
#pragma unroll
    for (int it = 0; it < 4; ++it) {
        int ln = it * 16 + rr;       // n offset
        ushort4 v;
#pragma unroll
        for (int j = 0; j < 4; ++j) v = (j == 0) ? (ushort4){tile[cc][ln], 0, 0, 0} : v, ((unsigned short*)&v)[j] = tile[cc + j][ln];
        *(ushort4*)(Wt + (size_t)(bx + ln) * DM + by + cc) = v;
    }
}

// ---------------- 128x128 GEMM, A[M][K] bf16 @ Bt[N][K] bf16 ----------------
// K-loop FROZEN (107 us qkv, 43% MfmaUtil, 0 bank conflicts). Epilogue modes:
//   MODE 0: bf16 C (Q)          MODE 1: f32 C (attn-out)
//   MODE 2: bf16 C -> LDS transpose tile -> COALESCED Vt[(b*16+h)*128+d][t] rows
//   MODE 3: bf16 C + RoPE via LDS tile (pairs d, d+64)
// smem: caller-provided (>= 16896 ushorts; As=smem, Bs=smem+8192).
template <int MODE>
static __device__ __forceinline__ void gemm_body(unsigned short* smem,
                                                 const unsigned short* __restrict__ A,
                                                 const unsigned short* __restrict__ Bt,
                                                 unsigned short* __restrict__ Cb,
                                                 float* __restrict__ Cf,
                                                 const float* __restrict__ cosp,
                                                 const float* __restrict__ sinp) {
    unsigned short* As = smem;
    unsigned short* Bs = smem + 8192;
    const int tid = threadIdx.x;
    const int w = tid >> 6, lane = tid & 63;
    const int col = lane & 15, quad = lane >> 4;
    const int wm = w >> 1, wn = w & 1;
    const size_t m0 = (size_t)blockIdx.y * 128;
    const size_t n0 = (size_t)blockIdx.x * 128;

    f32x4 acc[4][4];
#pragma unroll
    for (int i = 0; i < 4; ++i)
#pragma unroll
        for (int j = 0; j < 4; ++j)
            acc[i][j] = (f32x4){0.f, 0.f, 0.f, 0.f};

    const int lrow = lane >> 3;                 // 0..7 row within 8-row chunk
    const int gcol = ((lane & 7) ^ lrow) * 8;   // XOR-swizzled logical col (elems)

    for (int k0 = 0; k0 < DM; k0 += 64) {
#pragma unroll
        for (int c = w; c < 16; c += 4) {
            load_lds16(A + (m0 + c * 8 + lrow) * DM + k0 + gcol, &As[c * 512]);
            load_lds16(Bt + (n0 + c * 8 + lrow) * DM + k0 + gcol, &Bs[c * 512]);
        }
        __syncthreads();
#pragma unroll
        for (int ks = 0; ks < 2; ++ks) {
            short8 af[4], bf[4];
            int g = ks * 4 + quad;
#pragma unroll
            for (int mt = 0; mt < 4; ++mt) {
                int r = wm * 64 + mt * 16 + col;
                af[mt] = *(const short8*)&As[r * 64 + ((g ^ (r & 7)) * 8)];
            }
#pragma unroll
            for (int nt = 0; nt < 4; ++nt) {
                int r = wn * 64 + nt * 16 + col;
                bf[nt] = *(const short8*)&Bs[r * 64 + ((g ^ (r & 7)) * 8)];
            }
#pragma unroll
            for (int mt = 0; mt < 4; ++mt)
#pragma unroll
                for (int nt = 0; nt < 4; ++nt)
                    acc[mt][nt] = mfma_bf16(af[mt], bf[nt], acc[mt][nt]);
        }
        __syncthreads();
    }

    if (MODE == 0 || MODE == 1) {
#pragma unroll
        for (int mt = 0; mt < 4; ++mt)
#pragma unroll
            for (int nt = 0; nt < 4; ++nt)
#pragma unroll
                for (int reg = 0; reg < 4; ++reg) {
                    size_t r = m0 + wm * 64 + mt * 16 + quad * 4 + reg;
                    size_t c = n0 + wn * 64 + nt * 16 + col;
                    if (MODE == 1) Cf[r * DM + c] = acc[mt][nt][reg];
                    else           Cb[r * DM + c] = f2bf(acc[mt][nt][reg]);
                }
    } else if (MODE == 2) {
        // V: transpose via LDS tile [c_local][t_local], stride 132 (264 B == 0 mod 8:
        // all ushort4 accesses 8B-aligned; conflict-free), then coalesced row writes.
        unsigned short* tile = smem;   // 128*132 = 16896 ushorts
        const int tbl = wm * 64 + quad * 4;   // t_local base
#pragma unroll
        for (int mt = 0; mt < 4; ++mt)
#pragma unroll
            for (int nt = 0; nt < 4; ++nt) {
                const int cl = wn * 64 + nt * 16 + col;   // c local
                ushort4 v;
#pragma unroll
                for (int reg = 0; reg < 4; ++reg)
                    ((unsigned short*)&v)[reg] = f2bf(acc[mt][nt][reg]);
                *(ushort4*)&tile[cl * 132 + tbl + mt * 16] = v;
            }
        __syncthreads();
        const int bb = (int)(m0 >> 11);          // batch
        const int tg = (int)m0 & 2047;           // t base of this tile
        // 16 iters x 256 thr x 4 elems = 16384 = full 128x128 tile
#pragma unroll
        for (int i = 0; i < 16; ++i) {
            const int task = i * 256 + tid;      // 0..4095
            const int cl = task >> 5;            // 0..127 (row of Vt)
            const int tp = (task & 31) * 4;      // 0..124 (t offset, ushort4)
            ushort4 v = *(const ushort4*)&tile[cl * 132 + tp];
            *(ushort4*)(Cb + (size_t)(bb * 2048 + (int)n0 + cl) * T_SEQ + tg + tp) = v;
        }
    } else {
        // K: bf16 -> LDS tile [128][132] (128 cols + 4 pad), then RoPE pairs (d, d+64).
        // Bit-identical to old gemm->f2bf->k_rope_k path (bf16 intermediate kept).
        unsigned short* tile = smem;   // 128*132 = 16896 ushorts
#pragma unroll
        for (int mt = 0; mt < 4; ++mt)
#pragma unroll
            for (int nt = 0; nt < 4; ++nt)
#pragma unroll
                for (int reg = 0; reg < 4; ++reg) {
                    const int rl = wm * 64 + mt * 16 + quad * 4 + reg;
                    const int cl = wn * 64 + nt * 16 + col;
                    tile[rl * 132 + cl] = f2bf(acc[mt][nt][reg]);
                }
        __syncthreads();
#pragma unroll
        for (int i = 0; i < 8; ++i) {
            const int task = i * 256 + tid;
            const int rl = task >> 4;            // 0..127
            const int d4 = (task & 15) * 4;      // 0..60
            const int r = (int)m0 + rl;
            const int t = r & (T_SEQ - 1);
            ushort4 x1 = *(const ushort4*)&tile[rl * 132 + d4];
            ushort4 x2 = *(const ushort4*)&tile[rl * 132 + d4 + 64];
            float4 c = *(const float4*)(cosp + t * 64 + d4);
            float4 s = *(const float4*)(sinp + t * 64 + d4);
            ushort4 o1, o2;
#pragma unroll
            for (int q = 0; q < 4; ++q) {
                float a1 = bf2f(((const unsigned short*)&x1)[q]);
                float a2 = bf2f(((const unsigned short*)&x2)[q]);
                float cc = ((const float*)&c)[q], ss = ((const float*)&s)[q];
                ((unsigned short*)&o1)[q] = f2bf(a1 * cc - a2 * ss);
                ((unsigned short*)&o2)[q] = f2bf(a1 * ss + a2 * cc);
            }
            *(ushort4*)(Cb + (size_t)r * DM + n0 + d4)      = o1;
            *(ushort4*)(Cb + (size_t)r * DM + n0 + d4 + 64) = o2;
        }
    }
}

__global__ __launch_bounds__(256) void k_gemm_qkv(const unsigned short* __restrict__ xb,
                                                  const unsigned short* __restrict__ wtq,
                                                  const unsigned short* __restrict__ wtk,
                                                  const unsigned short* __restrict__ wtv,
                                                  unsigned short* __restrict__ qb,
                                                  unsigned short* __restrict__ kb,
                                                  unsigned short* __restrict__ vt,
                                                  const float* __restrict__ cosp,
                                                  const float* __restrict__ sinp) {
    __shared__ unsigned short smem[16896];   // 33 KiB: As/Bs (16K) or epilogue tile (16.9K)
    const int z = blockIdx.z;
    if (z == 0)      gemm_body<0>(smem, xb, wtq, qb, nullptr, nullptr, nullptr);
    else if (z == 1) gemm_body<3>(smem, xb, wtk, kb, nullptr, cosp, sinp);
    else             gemm_body<2>(smem, xb, wtv, vt, nullptr, nullptr, nullptr);
}

__global__ __launch_bounds__(256) void k_gemm_out(const unsigned short* __restrict__ ob,
                                                  const unsigned short* __restrict__ wto,
                                                  float* __restrict__ out) {
    __shared__ unsigned short smem[16384];
    gemm_body<1>(smem, ob, wto, nullptr, out, nullptr, nullptr);
}

// ---------------- causal flash attention, 32x32x16 MFMA, S^T formulation ----------------
// grid flat 512 blocks; LPT remap: j = 15 - (flat>>5) so longest blocks dispatch first.
// Block = 128 queries (4 waves x 32). Wave: S^T = K·Q^T (A=K-frag, B=Q-frag);
// per-lane softmax (col=query, 32 in-lane keys + shfl_xor(32)).
// r10: P^T redistribution moved from per-wave LDS (Ps, 18.4 KiB) to in-register
// packed-bf16 exchange via __shfl_xor(...,32). Derivation: lane (col,l5) holds
// s0[r] = P[4l5 + (r&3) + 8(r>>2)][col]; group q = r>>2 covers keys 8q+4l5+{0..3}.
// B-frag pb[st] needs keys st*16+l5*8+{0..7} = own group (2st+l5) + partner's group
// (2st+1-l5). Exchange that group packed as 2 u32; assemble low/high by l5.
// Removes 12 LDS ops + waits per tile; LDS 50.4 -> 32 KiB -> occupancy 3 -> 4+/CU.
__global__ __launch_bounds__(256) void k_flash(const unsigned short* __restrict__ Q,
                                               const unsigned short* __restrict__ K,
                                               const unsigned short* __restrict__ Vt,
                                               unsigned short* __restrict__ O,
                                               const float* __restrict__ cosp,
                                               const float* __restrict__ sinp) {
    __shared__ unsigned short Ks[64 * 128];
    __shared__ unsigned short Vs[128 * 64];
    const int tid = threadIdx.x;
    const int w = tid >> 6, lane = tid & 63;
    const int col = lane & 31, l5 = lane >> 5;
    const int flat = blockIdx.x | (blockIdx.y << 4) | (blockIdx.z << 8);
    const int j = 15 - (flat >> 5);
    const int hb = flat & 31;
    const int h = hb & 15, b = hb >> 4;
    const int q0 = j * 128;
    const size_t rowbase = ((size_t)b * T_SEQ) * DM + (size_t)h * HD;
    const size_t hbase = ((size_t)b * NH + h) * HD;
    const float SCL = 0.088388347648318447f * 1.4426950408889634f;  // 1/sqrt(D) * log2(e)

    const int t = q0 + w * 32 + col;     // this lane's query
    // ---- load Q fragments (B-layout: q=col, k=l5*8+jj per 16-chunk) + in-reg RoPE ----
    short8 qf[8];
    {
        const unsigned short* qp = Q + rowbase + (size_t)t * DM + l5 * 8;
#pragma unroll
        for (int st = 0; st < 8; ++st)
            qf[st] = *(const short8*)(qp + st * 16);
        const float* cp = cosp + t * 64 + l5 * 8;
        const float* sp = sinp + t * 64 + l5 * 8;
#pragma unroll
        for (int st = 0; st < 4; ++st) {
            float4 c0 = *(const float4*)(cp + st * 16);
            float4 c1 = *(const float4*)(cp + st * 16 + 4);
            float4 s0v = *(const float4*)(sp + st * 16);
            float4 s1v = *(const float4*)(sp + st * 16 + 4);
#pragma unroll
            for (int jj = 0; jj < 8; ++jj) {
                float cv = ((jj < 4) ? ((const float*)&c0)[jj] : ((const float*)&c1)[jj - 4]) * SCL;
                float sv = ((jj < 4) ? ((const float*)&s0v)[jj] : ((const float*)&s1v)[jj - 4]) * SCL;
                float a1 = bf2f((unsigned short)qf[st][jj]);
                float a2 = bf2f((unsigned short)qf[st + 4][jj]);
                qf[st][jj]     = (short)f2bf(a1 * cv - a2 * sv);
                qf[st + 4][jj] = (short)f2bf(a1 * sv + a2 * cv);
            }
        }
    }

    f32x16 o[4];
#pragma unroll
    for (int i = 0; i < 4; ++i) o[i] = (f32x16)(0.f);
    float m_i = -1e30f, l_i = 0.f;

    const int kt_max = 2 * j + 1;
    const int kt_lim = (q0 + w * 32 + 31) >> 6;   // last k-tile this wave computes
    const int cswz = col & 7;

    for (int kt = 0; kt <= kt_max; ++kt) {
        const int k0 = kt * 64;
        __syncthreads();
        // stage K tile [64 keys][128 d] and V^T tile [128 d][64 keys], XOR-swizzled
#pragma unroll
        for (int c = 0; c < 4; ++c) {
            const int c4 = w * 4 + c;
            const int krow = c4 * 4 + (lane >> 4);
            const int kpos = lane & 15;
            load_lds16(K + rowbase + (size_t)(k0 + krow) * DM + ((kpos ^ (krow & 7)) * 8),
                       &Ks[c4 * 512]);
            const int vrow = c4 * 8 + (lane >> 3);
            const int vpos = lane & 7;
            load_lds16(Vt + (hbase + vrow) * (size_t)T_SEQ + k0 + ((vpos ^ (vrow & 7)) * 8),
                       &Vs[c4 * 512]);
        }
        __syncthreads();
        if (kt > kt_lim) continue;   // wave-uniform; barriers still hit each iter

        // S^T = K·Q^T : two 32-key M-subtiles, 8 k-steps over D=128
        f32x16 s0 = (f32x16)(0.f), s1 = (f32x16)(0.f);
#pragma unroll
        for (int st = 0; st < 8; ++st) {
            const int dg = (2 * st + l5) ^ cswz;
            short8 kf0 = *(const short8*)&Ks[col * 128 + dg * 8];
            short8 kf1 = *(const short8*)&Ks[col * 128 + 4096 + dg * 8];
            s0 = mfma32_bf16(kf0, qf[st], s0);
            s1 = mfma32_bf16(kf1, qf[st], s1);
        }

        // causal mask (diag tiles only)
        if (k0 + 63 > q0 + w * 32) {
            const int kb = k0 + 4 * l5;
#pragma unroll
            for (int r = 0; r < 16; ++r) {
                const int key = kb + (r & 3) + 8 * (r >> 2);
                if (key > t) s0[r] = -1e30f;
                if (key + 32 > t) s1[r] = -1e30f;
            }
        }

        // per-lane online softmax (query=col; 32 in-lane keys + l5 partner)
        // T13 defer-max: keep m_i when all lanes' tile-max is within THR=8 (log2).
        float mx = -1e30f;
#pragma unroll
        for (int r = 0; r < 16; ++r) mx = fmaxf(mx, fmaxf(s0[r], s1[r]));
        mx = fmaxf(mx, __shfl_xor(mx, 32));
        if (!__all(mx - m_i <= 8.0f)) {
            const float mnew = fmaxf(m_i, mx);
            const float alpha = __builtin_amdgcn_exp2f(m_i - mnew);
            m_i = mnew;
            l_i *= alpha;
#pragma unroll
            for (int i = 0; i < 4; ++i) o[i] *= alpha;
        }
        float sum = 0.f;
#pragma unroll
        for (int r = 0; r < 16; ++r) {
            float p0 = __builtin_amdgcn_exp2f(s0[r] - m_i);
            float p1 = __builtin_amdgcn_exp2f(s1[r] - m_i);
            s0[r] = p0; s1[r] = p1;
            sum += p0 + p1;
        }
        sum += __shfl_xor(sum, 32);
        l_i += sum;

        // P^T -> B-frags fully in-register (no LDS): pack bf16 pairs, exchange the
        // partner's half-group via shfl_xor(32), assemble by l5.
        short8 pb[4];
#pragma unroll
        for (int st = 0; st < 2; ++st) {
            // ---- s0 (keys 0..31) -> pb[st] ----
            {
                unsigned pA0 = pk2(s0[8 * st + 0], s0[8 * st + 1]);   // group 2st
                unsigned pA1 = pk2(s0[8 * st + 2], s0[8 * st + 3]);
                unsigned pB0 = pk2(s0[8 * st + 4], s0[8 * st + 5]);   // group 2st+1
                unsigned pB1 = pk2(s0[8 * st + 6], s0[8 * st + 7]);
                unsigned sa = l5 ? pA0 : pB0, sb = l5 ? pA1 : pB1;    // send 2st+1-l5
                unsigned ra = __shfl_xor(sa, 32), rb = __shfl_xor(sb, 32);
                unsigned oa = l5 ? pB0 : pA0, ob = l5 ? pB1 : pA1;    // own 2st+l5
                uint4 wv = {l5 ? ra : oa, l5 ? rb : ob, l5 ? oa : ra, l5 ? ob : rb};
                pb[st] = __builtin_bit_cast(short8, wv);
            }
            // ---- s1 (keys 32..63) -> pb[st+2] ----
            {
                unsigned pA0 = pk2(s1[8 * st + 0], s1[8 * st + 1]);
                unsigned pA1 = pk2(s1[8 * st + 2], s1[8 * st + 3]);
                unsigned pB0 = pk2(s1[8 * st + 4], s1[8 * st + 5]);
                unsigned pB1 = pk2(s1[8 * st + 6], s1[8 * st + 7]);
                unsigned sa = l5 ? pA0 : pB0, sb = l5 ? pA1 : pB1;
                unsigned ra = __shfl_xor(sa, 32), rb = __shfl_xor(sb, 32);
                unsigned oa = l5 ? pB0 : pA0, ob = l5 ? pB1 : pA1;
                uint4 wv = {l5 ? ra : oa, l5 ? rb : ob, l5 ? oa : ra, l5 ? ob : rb};
                pb[st + 2] = __builtin_bit_cast(short8, wv);
            }
        }

        // O^T += V^T·P^T : A = V-frag (d rows), B = P-frag
#pragma unroll
        for (int ms = 0; ms < 4; ++ms) {
            const int drow = (ms * 32 + col) * 64;
#pragma unroll
            for (int st = 0; st < 4; ++st) {
                const int kg = (2 * st + l5) ^ cswz;
                short8 vf = *(const short8*)&Vs[drow + kg * 8];
                o[ms] = mfma32_bf16(vf, pb[st], o[ms]);
            }
        }
    }

    // epilogue: lane holds query=col, d = ms*32 + g*8 + 4*l5 + {0..3}
    const float inv = __builtin_amdgcn_rcpf(l_i);
    unsigned short* op = O + rowbase + (size_t)t * DM;
#pragma unroll
    for (int ms = 0; ms < 4; ++ms)
#pragma unroll
        for (int g = 0; g < 4; ++g) {
            ushort4 st4;
#pragma unroll
            for (int i = 0; i < 4; ++i)
                ((unsigned short*)&st4)[i] = bf_fast(o[ms][g * 4 + i] * inv);
            *(ushort4*)(op + ms * 32 + g * 8 + 4 * l5) = st4;
        }
}

extern "C" void kernel_launch(void* const* d_in, const int* in_sizes, int n_in,
                              void* d_out, int out_size, void* d_ws, size_t ws_size,
                              hipStream_t stream) {
    const float* x    = (const float*)d_in[0];
    // d_in[1] = mask (unused; causal structure is known)
    const float* cosp = (const float*)d_in[2];
    const float* sinp = (const float*)d_in[3];
    const float* Wq   = (const float*)d_in[4];
    const float* Wk   = (const float*)d_in[5];
    const float* Wv   = (const float*)d_in[6];
    const float* Wo   = (const float*)d_in[7];
    float* out = (float*)d_out;

    unsigned short* xb  = (unsigned short*)d_ws;             // 4096*2048
    unsigned short* wtq = xb  + (size_t)NROW * DM;           // 2048*2048 each
    unsigned short* wtk = wtq + (size_t)DM * DM;
    unsigned short* wtv = wtk + (size_t)DM * DM;
    unsigned short* wto = wtv + (size_t)DM * DM;
    unsigned short* qb  = wto + (size_t)DM * DM;             // 4096*2048 each
    unsigned short* kb  = qb  + (size_t)NROW * DM;
    unsigned short* vt  = kb  + (size_t)NROW * DM;           // V written TRANSPOSED here
    unsigned short* ob  = vt  + (size_t)NROW * DM;

    hipLaunchKernelGGL(k_prep, dim3(32, 32, 5), dim3(256), 0, stream,
                       x, xb, Wq, Wk, Wv, Wo, wtq, wtk, wtv, wto);
    hipLaunchKernelGGL(k_gemm_qkv, dim3(16, 32, 3), dim3(256), 0, stream,
                       xb, wtq, wtk, wtv, qb, kb, vt, cosp, sinp);
    hipLaunchKernelGGL(k_flash, dim3(16, 16, 2), dim3(256), 0, stream,
                       qb, kb, vt, ob, cosp, sinp);
    hipLaunchKernelGGL(k_gemm_out, dim3(16, 32, 1), dim3(256), 0, stream, ob, wto, out);
}

// Round 11
// 369.917 us; speedup vs baseline: 1.0335x; 1.0115x over previous
//
#include <hip/hip_runtime.h>

#define T_SEQ 2048
#define DM    2048
#define NH    16
#define HD    128
#define NROW  4096   // B*T

typedef __attribute__((ext_vector_type(8))) short short8;
typedef __attribute__((ext_vector_type(4))) float f32x4;
typedef __attribute__((ext_vector_type(16))) float f32x16;

static __device__ __forceinline__ float bf2f(unsigned short h) {
    unsigned int u = ((unsigned int)h) << 16;
    return __builtin_bit_cast(float, u);
}
static __device__ __forceinline__ unsigned short f2bf(float f) {
    unsigned int u = __builtin_bit_cast(unsigned int, f);
    u += 0x7FFFu + ((u >> 16) & 1u);
    return (unsigned short)(u >> 16);
}
// cheap round-half-up bf16 (2 VALU ops) for P/O inner-loop conversions
static __device__ __forceinline__ unsigned short bf_fast(float f) {
    return (unsigned short)((__builtin_bit_cast(unsigned int, f) + 0x8000u) >> 16);
}
// pack two floats to bf16x2 in a u32 (lo in low 16)
static __device__ __forceinline__ unsigned int pk2(float lo, float hi) {
    return (unsigned int)bf_fast(lo) | ((unsigned int)bf_fast(hi) << 16);
}

typedef __attribute__((address_space(1))) const unsigned int gas_uint;
typedef __attribute__((address_space(3))) unsigned int las_uint;

static __device__ __forceinline__ void load_lds16(const void* g, void* l) {
    __builtin_amdgcn_global_load_lds((gas_uint*)g, (las_uint*)l, 16, 0, 0);
}

static __device__ __forceinline__ f32x4 mfma_bf16(short8 a, short8 b, f32x4 c) {
    return __builtin_amdgcn_mfma_f32_16x16x32_bf16(a, b, c, 0, 0, 0);
}
static __device__ __forceinline__ f32x16 mfma32_bf16(short8 a, short8 b, f32x16 c) {
    return __builtin_amdgcn_mfma_f32_32x32x16_bf16(a, b, c, 0, 0, 0);
}

// ---------------- prep: z<4 -> transpose+cast W[k][n] f32 -> Wt[n][k] bf16 (64x64 tiles,
// float4 loads, bf16 LDS tile); z==4 -> cast x f32 -> bf16 (8 x float4 per thread) ------
__global__ __launch_bounds__(256) void k_prep(const float* __restrict__ x,
                                              unsigned short* __restrict__ xb,
                                              const float* __restrict__ w0, const float* __restrict__ w1,
                                              const float* __restrict__ w2, const float* __restrict__ w3,
                                              unsigned short* __restrict__ t0, unsigned short* __restrict__ t1,
                                              unsigned short* __restrict__ t2, unsigned short* __restrict__ t3) {
    const int tid = threadIdx.x;
    const int z = blockIdx.z;
    if (z == 4) {
        // cast: 1024 blocks cover NROW*DM = 8M elems; 8 x float4 per thread
        const int iblock = blockIdx.y * 32 + blockIdx.x;
#pragma unroll
        for (int i = 0; i < 8; ++i) {
            int idx = (iblock * 2048 + i * 256 + tid) * 4;
            float4 v = *(const float4*)(x + idx);
            ushort4 o;
            o.x = f2bf(v.x); o.y = f2bf(v.y); o.z = f2bf(v.z); o.w = f2bf(v.w);
            *(ushort4*)(xb + idx) = o;
        }
        return;
    }
    __shared__ unsigned short tile[64][68];   // tile[k][n], bf16
    const float* W = (z == 0) ? w0 : (z == 1) ? w1 : (z == 2) ? w2 : w3;
    unsigned short* Wt = (z == 0) ? t0 : (z == 1) ? t1 : (z == 2) ? t2 : t3;
    const int bx = blockIdx.x * 64;  // n base
    const int by = blockIdx.y * 64;  // k base
    const int rr = tid >> 4, cc = (tid & 15) * 4;
#pragma unroll
    for (int it = 0; it < 4; ++it) {
        int row = it * 16 + rr;      // k offset
        float4 v = *(const float4*)(W + (size_t)(by + row) * DM + bx + cc);
        ushort4 o;
        o.x = f2bf(v.x); o.y = f2bf(v.y); o.z = f2bf(v.z); o.w = f2bf(v.w);
        *(ushort4*)&tile[row][cc] = o;
    }
    __syncthreads();
#pragma unroll
    for (int it = 0; it < 4; ++it) {
        int ln = it * 16 + rr;       // n offset
        ushort4 v;
#pragma unroll
        for (int j = 0; j < 4; ++j) v = (j == 0) ? (ushort4){tile[cc][ln], 0, 0, 0} : v, ((unsigned short*)&v)[j] = tile[cc + j][ln];
        *(ushort4*)(Wt + (size_t)(bx + ln) * DM + by + cc) = v;
    }
}

// ---------------- 128x128 GEMM, A[M][K] bf16 @ Bt[N][K] bf16 ----------------
// K-loop FROZEN (107 us qkv, 43% MfmaUtil, 0 bank conflicts). Epilogue modes:
//   MODE 0: bf16 C (Q)          MODE 1: f32 C (attn-out)
//   MODE 2: bf16 C -> LDS transpose tile -> COALESCED Vt[(b*16+h)*128+d][t] rows
//   MODE 3: bf16 C + RoPE via LDS tile (pairs d, d+64)
// r11: m0/n0 passed in (XCD-region remap in wrappers). smem caller-provided.
template <int MODE>
static __device__ __forceinline__ void gemm_body(unsigned short* smem,
                                                 const unsigned short* __restrict__ A,
                                                 const unsigned short* __restrict__ Bt,
                                                 unsigned short* __restrict__ Cb,
                                                 float* __restrict__ Cf,
                                                 const float* __restrict__ cosp,
                                                 const float* __restrict__ sinp,
                                                 int m0i, int n0i) {
    unsigned short* As = smem;
    unsigned short* Bs = smem + 8192;
    const int tid = threadIdx.x;
    const int w = tid >> 6, lane = tid & 63;
    const int col = lane & 15, quad = lane >> 4;
    const int wm = w >> 1, wn = w & 1;
    const size_t m0 = (size_t)m0i;
    const size_t n0 = (size_t)n0i;

    f32x4 acc[4][4];
#pragma unroll
    for (int i = 0; i < 4; ++i)
#pragma unroll
        for (int j = 0; j < 4; ++j)
            acc[i][j] = (f32x4){0.f, 0.f, 0.f, 0.f};

    const int lrow = lane >> 3;                 // 0..7 row within 8-row chunk
    const int gcol = ((lane & 7) ^ lrow) * 8;   // XOR-swizzled logical col (elems)

    for (int k0 = 0; k0 < DM; k0 += 64) {
#pragma unroll
        for (int c = w; c < 16; c += 4) {
            load_lds16(A + (m0 + c * 8 + lrow) * DM + k0 + gcol, &As[c * 512]);
            load_lds16(Bt + (n0 + c * 8 + lrow) * DM + k0 + gcol, &Bs[c * 512]);
        }
        __syncthreads();
#pragma unroll
        for (int ks = 0; ks < 2; ++ks) {
            short8 af[4], bf[4];
            int g = ks * 4 + quad;
#pragma unroll
            for (int mt = 0; mt < 4; ++mt) {
                int r = wm * 64 + mt * 16 + col;
                af[mt] = *(const short8*)&As[r * 64 + ((g ^ (r & 7)) * 8)];
            }
#pragma unroll
            for (int nt = 0; nt < 4; ++nt) {
                int r = wn * 64 + nt * 16 + col;
                bf[nt] = *(const short8*)&Bs[r * 64 + ((g ^ (r & 7)) * 8)];
            }
#pragma unroll
            for (int mt = 0; mt < 4; ++mt)
#pragma unroll
                for (int nt = 0; nt < 4; ++nt)
                    acc[mt][nt] = mfma_bf16(af[mt], bf[nt], acc[mt][nt]);
        }
        __syncthreads();
    }

    if (MODE == 0 || MODE == 1) {
#pragma unroll
        for (int mt = 0; mt < 4; ++mt)
#pragma unroll
            for (int nt = 0; nt < 4; ++nt)
#pragma unroll
                for (int reg = 0; reg < 4; ++reg) {
                    size_t r = m0 + wm * 64 + mt * 16 + quad * 4 + reg;
                    size_t c = n0 + wn * 64 + nt * 16 + col;
                    if (MODE == 1) Cf[r * DM + c] = acc[mt][nt][reg];
                    else           Cb[r * DM + c] = f2bf(acc[mt][nt][reg]);
                }
    } else if (MODE == 2) {
        // V: transpose via LDS tile [c_local][t_local], stride 132 (264 B == 0 mod 8:
        // all ushort4 accesses 8B-aligned; conflict-free), then coalesced row writes.
        unsigned short* tile = smem;   // 128*132 = 16896 ushorts
        const int tbl = wm * 64 + quad * 4;   // t_local base
#pragma unroll
        for (int mt = 0; mt < 4; ++mt)
#pragma unroll
            for (int nt = 0; nt < 4; ++nt) {
                const int cl = wn * 64 + nt * 16 + col;   // c local
                ushort4 v;
#pragma unroll
                for (int reg = 0; reg < 4; ++reg)
                    ((unsigned short*)&v)[reg] = f2bf(acc[mt][nt][reg]);
                *(ushort4*)&tile[cl * 132 + tbl + mt * 16] = v;
            }
        __syncthreads();
        const int bb = m0i >> 11;                // batch
        const int tg = m0i & 2047;               // t base of this tile
        // 16 iters x 256 thr x 4 elems = 16384 = full 128x128 tile
#pragma unroll
        for (int i = 0; i < 16; ++i) {
            const int task = i * 256 + tid;      // 0..4095
            const int cl = task >> 5;            // 0..127 (row of Vt)
            const int tp = (task & 31) * 4;      // 0..124 (t offset, ushort4)
            ushort4 v = *(const ushort4*)&tile[cl * 132 + tp];
            *(ushort4*)(Cb + (size_t)(bb * 2048 + n0i + cl) * T_SEQ + tg + tp) = v;
        }
    } else {
        // K: bf16 -> LDS tile [128][132] (128 cols + 4 pad), then RoPE pairs (d, d+64).
        // Bit-identical to old gemm->f2bf->k_rope_k path (bf16 intermediate kept).
        unsigned short* tile = smem;   // 128*132 = 16896 ushorts
#pragma unroll
        for (int mt = 0; mt < 4; ++mt)
#pragma unroll
            for (int nt = 0; nt < 4; ++nt)
#pragma unroll
                for (int reg = 0; reg < 4; ++reg) {
                    const int rl = wm * 64 + mt * 16 + quad * 4 + reg;
                    const int cl = wn * 64 + nt * 16 + col;
                    tile[rl * 132 + cl] = f2bf(acc[mt][nt][reg]);
                }
        __syncthreads();
#pragma unroll
        for (int i = 0; i < 8; ++i) {
            const int task = i * 256 + tid;
            const int rl = task >> 4;            // 0..127
            const int d4 = (task & 15) * 4;      // 0..60
            const int r = m0i + rl;
            const int t = r & (T_SEQ - 1);
            ushort4 x1 = *(const ushort4*)&tile[rl * 132 + d4];
            ushort4 x2 = *(const ushort4*)&tile[rl * 132 + d4 + 64];
            float4 c = *(const float4*)(cosp + t * 64 + d4);
            float4 s = *(const float4*)(sinp + t * 64 + d4);
            ushort4 o1, o2;
#pragma unroll
            for (int q = 0; q < 4; ++q) {
                float a1 = bf2f(((const unsigned short*)&x1)[q]);
                float a2 = bf2f(((const unsigned short*)&x2)[q]);
                float cc = ((const float*)&c)[q], ss = ((const float*)&s)[q];
                ((unsigned short*)&o1)[q] = f2bf(a1 * cc - a2 * ss);
                ((unsigned short*)&o2)[q] = f2bf(a1 * ss + a2 * cc);
            }
            *(ushort4*)(Cb + (size_t)r * DM + n0 + d4)      = o1;
            *(ushort4*)(Cb + (size_t)r * DM + n0 + d4 + 64) = o2;
        }
    }
}

// r11: XCD-region remap (T1, isolated). Assumes XCD = blockIdx % 8 round-robin.
// Each XCD owns an 8x8 tile region per z: working set 4MB A-panels + 4MB weights
// (vs 16MB A + 1MB W with row-major dispatch) against the 4MB per-XCD L2.
// Bijection (qkv, 1536 blocks): f = (xcd) + 8*(idx + 64*z); x = (xcd&1)*8 + (idx&7),
// y = (xcd>>1)*8 + (idx>>3). Covers x in 0..15, y in 0..31, z in 0..2 exactly once.
__global__ __launch_bounds__(256) void k_gemm_qkv(const unsigned short* __restrict__ xb,
                                                  const unsigned short* __restrict__ wtq,
                                                  const unsigned short* __restrict__ wtk,
                                                  const unsigned short* __restrict__ wtv,
                                                  unsigned short* __restrict__ qb,
                                                  unsigned short* __restrict__ kb,
                                                  unsigned short* __restrict__ vt,
                                                  const float* __restrict__ cosp,
                                                  const float* __restrict__ sinp) {
    __shared__ unsigned short smem[16896];   // 33 KiB: As/Bs (16K) or epilogue tile (16.9K)
    const int f = blockIdx.x;
    const int xcd = f & 7, i = f >> 3;       // i in 0..191
    const int z = i >> 6, idx = i & 63;
    const int tx = (xcd & 1) * 8 + (idx & 7);
    const int ty = (xcd >> 1) * 8 + (idx >> 3);
    const int m0i = ty * 128, n0i = tx * 128;
    if (z == 0)      gemm_body<0>(smem, xb, wtq, qb, nullptr, nullptr, nullptr, m0i, n0i);
    else if (z == 1) gemm_body<3>(smem, xb, wtk, kb, nullptr, cosp, sinp, m0i, n0i);
    else             gemm_body<2>(smem, xb, wtv, vt, nullptr, nullptr, nullptr, m0i, n0i);
}

__global__ __launch_bounds__(256) void k_gemm_out(const unsigned short* __restrict__ ob,
                                                  const unsigned short* __restrict__ wto,
                                                  float* __restrict__ out) {
    __shared__ unsigned short smem[16384];
    const int f = blockIdx.x;                // 512 blocks
    const int xcd = f & 7, idx = f >> 3;     // idx in 0..63
    const int tx = (xcd & 1) * 8 + (idx & 7);
    const int ty = (xcd >> 1) * 8 + (idx >> 3);
    gemm_body<1>(smem, ob, wto, nullptr, out, nullptr, nullptr, ty * 128, tx * 128);
}

// ---------------- causal flash attention, 32x32x16 MFMA, S^T formulation ----------------
// grid flat 512 blocks; LPT remap: j = 15 - (flat>>5) so longest blocks dispatch first.
// Block = 128 queries (4 waves x 32). Wave: S^T = K·Q^T (A=K-frag, B=Q-frag);
// per-lane softmax (col=query, 32 in-lane keys + shfl_xor(32)).
// r10: P^T redistribution fully in-register (packed bf16 + shfl_xor(32)); no Ps LDS.
__global__ __launch_bounds__(256) void k_flash(const unsigned short* __restrict__ Q,
                                               const unsigned short* __restrict__ K,
                                               const unsigned short* __restrict__ Vt,
                                               unsigned short* __restrict__ O,
                                               const float* __restrict__ cosp,
                                               const float* __restrict__ sinp) {
    __shared__ unsigned short Ks[64 * 128];
    __shared__ unsigned short Vs[128 * 64];
    const int tid = threadIdx.x;
    const int w = tid >> 6, lane = tid & 63;
    const int col = lane & 31, l5 = lane >> 5;
    const int flat = blockIdx.x | (blockIdx.y << 4) | (blockIdx.z << 8);
    const int j = 15 - (flat >> 5);
    const int hb = flat & 31;
    const int h = hb & 15, b = hb >> 4;
    const int q0 = j * 128;
    const size_t rowbase = ((size_t)b * T_SEQ) * DM + (size_t)h * HD;
    const size_t hbase = ((size_t)b * NH + h) * HD;
    const float SCL = 0.088388347648318447f * 1.4426950408889634f;  // 1/sqrt(D) * log2(e)

    const int t = q0 + w * 32 + col;     // this lane's query
    // ---- load Q fragments (B-layout: q=col, k=l5*8+jj per 16-chunk) + in-reg RoPE ----
    short8 qf[8];
    {
        const unsigned short* qp = Q + rowbase + (size_t)t * DM + l5 * 8;
#pragma unroll
        for (int st = 0; st < 8; ++st)
            qf[st] = *(const short8*)(qp + st * 16);
        const float* cp = cosp + t * 64 + l5 * 8;
        const float* sp = sinp + t * 64 + l5 * 8;
#pragma unroll
        for (int st = 0; st < 4; ++st) {
            float4 c0 = *(const float4*)(cp + st * 16);
            float4 c1 = *(const float4*)(cp + st * 16 + 4);
            float4 s0v = *(const float4*)(sp + st * 16);
            float4 s1v = *(const float4*)(sp + st * 16 + 4);
#pragma unroll
            for (int jj = 0; jj < 8; ++jj) {
                float cv = ((jj < 4) ? ((const float*)&c0)[jj] : ((const float*)&c1)[jj - 4]) * SCL;
                float sv = ((jj < 4) ? ((const float*)&s0v)[jj] : ((const float*)&s1v)[jj - 4]) * SCL;
                float a1 = bf2f((unsigned short)qf[st][jj]);
                float a2 = bf2f((unsigned short)qf[st + 4][jj]);
                qf[st][jj]     = (short)f2bf(a1 * cv - a2 * sv);
                qf[st + 4][jj] = (short)f2bf(a1 * sv + a2 * cv);
            }
        }
    }

    f32x16 o[4];
#pragma unroll
    for (int i = 0; i < 4; ++i) o[i] = (f32x16)(0.f);
    float m_i = -1e30f, l_i = 0.f;

    const int kt_max = 2 * j + 1;
    const int kt_lim = (q0 + w * 32 + 31) >> 6;   // last k-tile this wave computes
    const int cswz = col & 7;

    for (int kt = 0; kt <= kt_max; ++kt) {
        const int k0 = kt * 64;
        __syncthreads();
        // stage K tile [64 keys][128 d] and V^T tile [128 d][64 keys], XOR-swizzled
#pragma unroll
        for (int c = 0; c < 4; ++c) {
            const int c4 = w * 4 + c;
            const int krow = c4 * 4 + (lane >> 4);
            const int kpos = lane & 15;
            load_lds16(K + rowbase + (size_t)(k0 + krow) * DM + ((kpos ^ (krow & 7)) * 8),
                       &Ks[c4 * 512]);
            const int vrow = c4 * 8 + (lane >> 3);
            const int vpos = lane & 7;
            load_lds16(Vt + (hbase + vrow) * (size_t)T_SEQ + k0 + ((vpos ^ (vrow & 7)) * 8),
                       &Vs[c4 * 512]);
        }
        __syncthreads();
        if (kt > kt_lim) continue;   // wave-uniform; barriers still hit each iter

        // S^T = K·Q^T : two 32-key M-subtiles, 8 k-steps over D=128
        f32x16 s0 = (f32x16)(0.f), s1 = (f32x16)(0.f);
#pragma unroll
        for (int st = 0; st < 8; ++st) {
            const int dg = (2 * st + l5) ^ cswz;
            short8 kf0 = *(const short8*)&Ks[col * 128 + dg * 8];
            short8 kf1 = *(const short8*)&Ks[col * 128 + 4096 + dg * 8];
            s0 = mfma32_bf16(kf0, qf[st], s0);
            s1 = mfma32_bf16(kf1, qf[st], s1);
        }

        // causal mask (diag tiles only)
        if (k0 + 63 > q0 + w * 32) {
            const int kb = k0 + 4 * l5;
#pragma unroll
            for (int r = 0; r < 16; ++r) {
                const int key = kb + (r & 3) + 8 * (r >> 2);
                if (key > t) s0[r] = -1e30f;
                if (key + 32 > t) s1[r] = -1e30f;
            }
        }

        // per-lane online softmax (query=col; 32 in-lane keys + l5 partner)
        // T13 defer-max: keep m_i when all lanes' tile-max is within THR=8 (log2).
        float mx = -1e30f;
#pragma unroll
        for (int r = 0; r < 16; ++r) mx = fmaxf(mx, fmaxf(s0[r], s1[r]));
        mx = fmaxf(mx, __shfl_xor(mx, 32));
        if (!__all(mx - m_i <= 8.0f)) {
            const float mnew = fmaxf(m_i, mx);
            const float alpha = __builtin_amdgcn_exp2f(m_i - mnew);
            m_i = mnew;
            l_i *= alpha;
#pragma unroll
            for (int i = 0; i < 4; ++i) o[i] *= alpha;
        }
        float sum = 0.f;
#pragma unroll
        for (int r = 0; r < 16; ++r) {
            float p0 = __builtin_amdgcn_exp2f(s0[r] - m_i);
            float p1 = __builtin_amdgcn_exp2f(s1[r] - m_i);
            s0[r] = p0; s1[r] = p1;
            sum += p0 + p1;
        }
        sum += __shfl_xor(sum, 32);
        l_i += sum;

        // P^T -> B-frags fully in-register (no LDS): pack bf16 pairs, exchange the
        // partner's half-group via shfl_xor(32), assemble by l5.
        short8 pb[4];
#pragma unroll
        for (int st = 0; st < 2; ++st) {
            {
                unsigned pA0 = pk2(s0[8 * st + 0], s0[8 * st + 1]);   // group 2st
                unsigned pA1 = pk2(s0[8 * st + 2], s0[8 * st + 3]);
                unsigned pB0 = pk2(s0[8 * st + 4], s0[8 * st + 5]);   // group 2st+1
                unsigned pB1 = pk2(s0[8 * st + 6], s0[8 * st + 7]);
                unsigned sa = l5 ? pA0 : pB0, sb = l5 ? pA1 : pB1;    // send 2st+1-l5
                unsigned ra = __shfl_xor(sa, 32), rb = __shfl_xor(sb, 32);
                unsigned oa = l5 ? pB0 : pA0, ob = l5 ? pB1 : pA1;    // own 2st+l5
                uint4 wv = {l5 ? ra : oa, l5 ? rb : ob, l5 ? oa : ra, l5 ? ob : rb};
                pb[st] = __builtin_bit_cast(short8, wv);
            }
            {
                unsigned pA0 = pk2(s1[8 * st + 0], s1[8 * st + 1]);
                unsigned pA1 = pk2(s1[8 * st + 2], s1[8 * st + 3]);
                unsigned pB0 = pk2(s1[8 * st + 4], s1[8 * st + 5]);
                unsigned pB1 = pk2(s1[8 * st + 6], s1[8 * st + 7]);
                unsigned sa = l5 ? pA0 : pB0, sb = l5 ? pA1 : pB1;
                unsigned ra = __shfl_xor(sa, 32), rb = __shfl_xor(sb, 32);
                unsigned oa = l5 ? pB0 : pA0, ob = l5 ? pB1 : pA1;
                uint4 wv = {l5 ? ra : oa, l5 ? rb : ob, l5 ? oa : ra, l5 ? ob : rb};
                pb[st + 2] = __builtin_bit_cast(short8, wv);
            }
        }

        // O^T += V^T·P^T : A = V-frag (d rows), B = P-frag
#pragma unroll
        for (int ms = 0; ms < 4; ++ms) {
            const int drow = (ms * 32 + col) * 64;
#pragma unroll
            for (int st = 0; st < 4; ++st) {
                const int kg = (2 * st + l5) ^ cswz;
                short8 vf = *(const short8*)&Vs[drow + kg * 8];
                o[ms] = mfma32_bf16(vf, pb[st], o[ms]);
            }
        }
    }

    // epilogue: lane holds query=col, d = ms*32 + g*8 + 4*l5 + {0..3}
    const float inv = __builtin_amdgcn_rcpf(l_i);
    unsigned short* op = O + rowbase + (size_t)t * DM;
#pragma unroll
    for (int ms = 0; ms < 4; ++ms)
#pragma unroll
        for (int g = 0; g < 4; ++g) {
            ushort4 st4;
#pragma unroll
            for (int i = 0; i < 4; ++i)
                ((unsigned short*)&st4)[i] = bf_fast(o[ms][g * 4 + i] * inv);
            *(ushort4*)(op + ms * 32 + g * 8 + 4 * l5) = st4;
        }
}

extern "C" void kernel_launch(void* const* d_in, const int* in_sizes, int n_in,
                              void* d_out, int out_size, void* d_ws, size_t ws_size,
                              hipStream_t stream) {
    const float* x    = (const float*)d_in[0];
    // d_in[1] = mask (unused; causal structure is known)
    const float* cosp = (const float*)d_in[2];
    const float* sinp = (const float*)d_in[3];
    const float* Wq   = (const float*)d_in[4];
    const float* Wk   = (const float*)d_in[5];
    const float* Wv   = (const float*)d_in[6];
    const float* Wo   = (const float*)d_in[7];
    float* out = (float*)d_out;

    unsigned short* xb  = (unsigned short*)d_ws;             // 4096*2048
    unsigned short* wtq = xb  + (size_t)NROW * DM;           // 2048*2048 each
    unsigned short* wtk = wtq + (size_t)DM * DM;
    unsigned short* wtv = wtk + (size_t)DM * DM;
    unsigned short* wto = wtv + (size_t)DM * DM;
    unsigned short* qb  = wto + (size_t)DM * DM;             // 4096*2048 each
    unsigned short* kb  = qb  + (size_t)NROW * DM;
    unsigned short* vt  = kb  + (size_t)NROW * DM;           // V written TRANSPOSED here
    unsigned short* ob  = vt  + (size_t)NROW * DM;

    hipLaunchKernelGGL(k_prep, dim3(32, 32, 5), dim3(256), 0, stream,
                       x, xb, Wq, Wk, Wv, Wo, wtq, wtk, wtv, wto);
    hipLaunchKernelGGL(k_gemm_qkv, dim3(1536), dim3(256), 0, stream,
                       xb, wtq, wtk, wtv, qb, kb, vt, cosp, sinp);
    hipLaunchKernelGGL(k_flash, dim3(16, 16, 2), dim3(256), 0, stream,
                       qb, kb, vt, ob, cosp, sinp);
    hipLaunchKernelGGL(k_gemm_out, dim3(512), dim3(256), 0, stream, ob, wto, out);
}